// Round 16
// baseline (24.410 us; speedup 1.0000x reference)
//
#include <hip/hip_runtime.h>
#include <stdint.h>

typedef __attribute__((ext_vector_type(4)))  int i32x4;
typedef __attribute__((ext_vector_type(16))) int i32x16;
typedef __attribute__((ext_vector_type(2)))  float f32x2;

// ws layout:
//   xm: uint4 [b=512][z=8][s=16]  (4 x u32 k-bitplanes)   1 MB
//   Bp: i8    [z=8][p=2][sl=8][j=128][k=128]              2 MB
//   mk: u16   [z=8][j=128]   live-tile mask               2 KB
#define XM_OFF 0u
#define BP_OFF 1048576u
#define MK_OFF 3145728u

__device__ __forceinline__ uint32_t q16(float v){
  float f = fminf(fmaxf(rintf(v*4096.f), -32768.f), 32767.f);
  return (uint32_t)(int)f & 0xffffu;
}

// ---------- fused pack: x -> bit-planes, w -> slice planes + per-j masks, out <- bias ----------
__global__ __launch_bounds__(256) void pack_k(const float* __restrict__ x, const float* __restrict__ w,
                                              const float* __restrict__ bias,
                                              uint4* __restrict__ xm, uint32_t* __restrict__ Bw,
                                              uint16_t* __restrict__ mk, float* __restrict__ out){
  const int lane = threadIdx.x & 63;
  if (blockIdx.x < 1024){
    // one wave per (b, z): transpose 128 xint16 values into 16 s-bitplanes of 4 u32
    int wv = blockIdx.x*4 + (threadIdx.x >> 6);       // 0..4095
    int b = wv >> 3, z = wv & 7;
    const float* xp = x + b*1024 + z*128;
    uint32_t u0 = q16(xp[lane]);
    uint32_t u1 = q16(xp[lane + 64]);
    uint4 out4 = {0,0,0,0};
    #pragma unroll
    for (int s = 0; s < 16; ++s){
      unsigned long long m0 = __ballot((u0 >> s) & 1u);
      unsigned long long m1 = __ballot((u1 >> s) & 1u);
      if (lane == s){
        out4.x = (uint32_t)m0; out4.y = (uint32_t)(m0 >> 32);
        out4.z = (uint32_t)m1; out4.w = (uint32_t)(m1 >> 32);
      }
    }
    if (lane < 16) xm[(b*8 + z)*16 + lane] = out4;
  } else if (blockIdx.x < 1152){
    int t = (blockIdx.x - 1024)*256 + threadIdx.x;    // 32768; one j per block
    int j = t >> 8, kq = t & 255;
    int r = kq >> 5, kd = kq & 31;                    // each 32-lane half: one r
    float4 v = *reinterpret_cast<const float4*>(w + j*1024 + kq*4);
    uint32_t lm = 0;
    #pragma unroll
    for (int p = 0; p < 2; ++p){
      uint32_t q0 = (uint32_t)fminf(rintf(fmaxf(p ? -v.x : v.x, 0.f)*4096.f), 65535.f);
      uint32_t q1 = (uint32_t)fminf(rintf(fmaxf(p ? -v.y : v.y, 0.f)*4096.f), 65535.f);
      uint32_t q2 = (uint32_t)fminf(rintf(fmaxf(p ? -v.z : v.z, 0.f)*4096.f), 65535.f);
      uint32_t q3 = (uint32_t)fminf(rintf(fmaxf(p ? -v.w : v.w, 0.f)*4096.f), 65535.f);
      #pragma unroll
      for (int sl = 0; sl < 8; ++sl){
        int sh = 2*(7 - sl);
        uint32_t word = ((q0 >> sh) & 3u) | (((q1 >> sh) & 3u) << 8)
                      | (((q2 >> sh) & 3u) << 16) | (((q3 >> sh) & 3u) << 24);
        Bw[(((r*2 + p)*8 + sl)*128 + j)*32 + kd] = word;
        lm |= (word != 0u ? 1u : 0u) << (p*8 + sl);
      }
    }
    // OR-reduce within each 32-lane half (half shares same (r, j))
    lm |= (uint32_t)__shfl_xor((int)lm, 16);
    lm |= (uint32_t)__shfl_xor((int)lm, 8);
    lm |= (uint32_t)__shfl_xor((int)lm, 4);
    lm |= (uint32_t)__shfl_xor((int)lm, 2);
    lm |= (uint32_t)__shfl_xor((int)lm, 1);
    if ((threadIdx.x & 31) == 0) mk[r*128 + j] = (uint16_t)lm;  // one writer per (z,j): race-free
  } else {
    // out <- bias rounded to 2^-12 grid: all later atomic adds are exact & order-free
    int t = (blockIdx.x - 1152)*256 + threadIdx.x;    // 65536
    out[t] = rintf(bias[t & 127]*4096.f)*(1.0f/4096.0f);
  }
}

// ---------- main MFMA kernel: r15 body + packed-2xf32 EPI (v_pk_fma_f32) ----------
__global__ __launch_bounds__(512, 4) void mvm_main_k(const uint4* __restrict__ xm,
                                                     const uint8_t* __restrict__ Bp,
                                                     const uint16_t* __restrict__ mk,
                                                     float* __restrict__ out){
  __shared__ uint8_t lds[65536];                      // 16 (p,sl) slots x 4KB
  const int tid = threadIdx.x, lane = tid & 63, wid = tid >> 6;
  const int z = blockIdx.z, jblk = blockIdx.y;
  const int col = lane & 31, hi = lane >> 5;

  // ---- wave-uniform live mask for (z, jblk): OR of 32 per-j masks ----
  uint32_t mv = ((const uint32_t*)mk)[z*64 + jblk*16 + (lane & 15)];
  mv |= (uint32_t)__shfl_xor((int)mv, 1);
  mv |= (uint32_t)__shfl_xor((int)mv, 2);
  mv |= (uint32_t)__shfl_xor((int)mv, 4);
  mv |= (uint32_t)__shfl_xor((int)mv, 8);
  const uint32_t msk = (uint32_t)__builtin_amdgcn_readfirstlane((int)((mv | (mv >> 16)) & 0xFFFFu));

  // ---- stage live (p,sl) tiles only, swizzled (chunk ^= row&7), ti-indexed slots ----
  {
    const int q = lane >> 3, cS = (lane & 7) ^ q;
    #pragma unroll
    for (int u = 0; u < 2; ++u){
      const int si = wid + u*8;
      if (msk & (1u << si)){
        const uint8_t* src = Bp + ((size_t)((z*16 + si)*128 + jblk*32) << 7);
        uint4 r0 = *(const uint4*)(src + (q     )*128 + cS*16);
        uint4 r1 = *(const uint4*)(src + (q +  8)*128 + cS*16);
        uint4 r2 = *(const uint4*)(src + (q + 16)*128 + cS*16);
        uint4 r3 = *(const uint4*)(src + (q + 24)*128 + cS*16);
        uint8_t* dst = lds + si*4096 + lane*16;
        *(uint4*)(dst       ) = r0;
        *(uint4*)(dst + 1024) = r1;
        *(uint4*)(dst + 2048) = r2;
        *(uint4*)(dst + 3072) = r3;
      }
    }
  }

  // ---- A fragments for TWO b-pairs (4 b per wave), verified mapping ----
  const int bb  = blockIdx.x*32 + wid*4;
  const int s_a = lane & 15;
  const uint4 pwA = xm[((bb     + (col >> 4))*8 + z)*16 + s_a];
  const uint4 pwB = xm[((bb + 2 + (col >> 4))*8 + z)*16 + s_a];
  i32x4 afrA[4], afrB[4];
  {
    const uint32_t wA[4] = {pwA.x, pwA.y, pwA.z, pwA.w};
    const uint32_t wB[4] = {pwB.x, pwB.y, pwB.z, pwB.w};
    #pragma unroll
    for (int f = 0; f < 4; ++f){
      uint32_t plA = wA[f] >> (hi*16);
      uint32_t plB = wB[f] >> (hi*16);
      #pragma unroll
      for (int wI = 0; wI < 4; ++wI){
        afrA[f][wI] = (int)((((plA >> (wI*4)) & 0xFu) * 0x204081u) & 0x01010101u);
        afrB[f][wI] = (int)((((plB >> (wI*4)) & 0xFu) * 0x204081u) & 0x01010101u);
      }
    }
  }
  __syncthreads();

  const int c7 = col & 7;
  const int xo0 = ((0 + hi) ^ c7) << 4;
  const int xo1 = ((2 + hi) ^ c7) << 4;
  const int xo2 = ((4 + hi) ^ c7) << 4;
  const int xo3 = ((6 + hi) ^ c7) << 4;

  i32x16 zz;
  #pragma unroll
  for (int i = 0; i < 16; ++i) zz[i] = 0;

  const float C1 = (float)(511.0/384.0);
  const float QC = (float)(384.0/511.0/4096.0);
  const float sc = hi ? 16.0f : 1.0f;                 // 2^(4*hi)
  const float w7 = hi ? -8.0f : 8.0f;                 // stream 15 (s_lo=11, hi=1) is negative
  // packed constants (each lane holds {A0-half, A1-half} in the 2 packed slots)
  const f32x2 kC1 = {C1, C1};
  const f32x2 kM  = {8388608.f, 8388608.f};           // 2^23 magic: fma(c,C1,2^23) = rint(c*C1)+2^23
  const f32x2 kMn = {-8388608.f, -8388608.f};
  const f32x2 k2  = {2.f, 2.f};
  const f32x2 k4  = {4.f, 4.f};
  const f32x2 k8  = {8.f, 8.f};
  const f32x2 kw7 = {w7, w7};
  float oA0 = 0.f, oA1 = 0.f, oB0 = 0.f, oB1 = 0.f;

  // wave-parity phase stagger: odd waves run p=1 first (scalar-uniform)
  const int pfirst = __builtin_amdgcn_readfirstlane(wid & 1);

// packed EPI: pair counts (g, g+8) -> packed lanes {A0-half, A1-half}; identical tree coeffs.
// biased round (exact): fma(c, C1, 2^23) - 2^23 == rint(c*C1)  (c*C1 <= 511 << 2^24, RNE)
#define EPI(cc, accv) do { \
    f32x2 n0, n1, n2, n3, m0, m1, m2, m3; \
    n0.x = (float)cc[0];  n0.y = (float)cc[8]; \
    n1.x = (float)cc[1];  n1.y = (float)cc[9]; \
    n2.x = (float)cc[2];  n2.y = (float)cc[10]; \
    n3.x = (float)cc[3];  n3.y = (float)cc[11]; \
    m0.x = (float)cc[4];  m0.y = (float)cc[12]; \
    m1.x = (float)cc[5];  m1.y = (float)cc[13]; \
    m2.x = (float)cc[6];  m2.y = (float)cc[14]; \
    m3.x = (float)cc[7];  m3.y = (float)cc[15]; \
    n0 = __builtin_elementwise_fma(n0, kC1, kM) + kMn; \
    n1 = __builtin_elementwise_fma(n1, kC1, kM) + kMn; \
    n2 = __builtin_elementwise_fma(n2, kC1, kM) + kMn; \
    n3 = __builtin_elementwise_fma(n3, kC1, kM) + kMn; \
    m0 = __builtin_elementwise_fma(m0, kC1, kM) + kMn; \
    m1 = __builtin_elementwise_fma(m1, kC1, kM) + kMn; \
    m2 = __builtin_elementwise_fma(m2, kC1, kM) + kMn; \
    m3 = __builtin_elementwise_fma(m3, kC1, kM) + kMn; \
    f32x2 t0 = __builtin_elementwise_fma(n1, k2, n0); \
    t0 = __builtin_elementwise_fma(n2, k4, t0); \
    t0 = __builtin_elementwise_fma(n3, k8, t0); \
    f32x2 t1 = __builtin_elementwise_fma(m1, k2, m0); \
    t1 = __builtin_elementwise_fma(m2, k4, t1); \
    t1 = __builtin_elementwise_fma(m3, kw7, t1); \
    accv = __builtin_elementwise_fma(t0, slp,  accv); \
    accv = __builtin_elementwise_fma(t1, slp2, accv); \
  } while (0)

  #pragma unroll
  for (int pi = 0; pi < 2; ++pi){
    const int p = pi ^ pfirst;                        // scalar-uniform
    const int tbase = p*8;
    f32x2 accA = {0.f, 0.f}, accB = {0.f, 0.f};       // {A0-half, A1-half}
    #pragma unroll
    for (int sl = 0; sl < 8; ++sl){
      if (msk & (1u << (tbase + sl))){
        const float slwv   = (float)(1 << (14 - 2*sl));  // 4^(7-sl)
        const f32x2 slp  = {slwv, slwv};
        const f32x2 slp2 = {slwv*256.0f, slwv*256.0f};
        const uint8_t* lb = lds + (size_t)(tbase + sl)*4096 + col*128;
        i32x4 b0 = *(const i32x4*)(lb + xo0);
        i32x4 b1 = *(const i32x4*)(lb + xo1);
        i32x4 b2 = *(const i32x4*)(lb + xo2);
        i32x4 b3 = *(const i32x4*)(lb + xo3);
        // interleaved independent chains: matrix pipe gets an issue-ready MFMA every slot
        i32x16 cc = __builtin_amdgcn_mfma_i32_32x32x32_i8(afrA[0], b0, zz, 0, 0, 0);
        i32x16 cd = __builtin_amdgcn_mfma_i32_32x32x32_i8(afrB[0], b0, zz, 0, 0, 0);
        cc = __builtin_amdgcn_mfma_i32_32x32x32_i8(afrA[1], b1, cc, 0, 0, 0);
        cd = __builtin_amdgcn_mfma_i32_32x32x32_i8(afrB[1], b1, cd, 0, 0, 0);
        cc = __builtin_amdgcn_mfma_i32_32x32x32_i8(afrA[2], b2, cc, 0, 0, 0);
        cd = __builtin_amdgcn_mfma_i32_32x32x32_i8(afrB[2], b2, cd, 0, 0, 0);
        cc = __builtin_amdgcn_mfma_i32_32x32x32_i8(afrA[3], b3, cc, 0, 0, 0);
        cd = __builtin_amdgcn_mfma_i32_32x32x32_i8(afrB[3], b3, cd, 0, 0, 0);
        EPI(cc, accA);
        EPI(cd, accB);
      }
    }

    float aA0 = accA.x*sc, aA1 = accA.y*sc, aB0 = accB.x*sc, aB1 = accB.y*sc;
    aA0 += __shfl_xor(aA0, 32); aA1 += __shfl_xor(aA1, 32);
    aB0 += __shfl_xor(aB0, 32); aB1 += __shfl_xor(aB1, 32);

    float qA0 = fminf(fmaxf(rintf(aA0*QC)*(1.0f/4096.0f), -8.0f), 8.0f - 1.0f/4096.0f);
    float qA1 = fminf(fmaxf(rintf(aA1*QC)*(1.0f/4096.0f), -8.0f), 8.0f - 1.0f/4096.0f);
    float qB0 = fminf(fmaxf(rintf(aB0*QC)*(1.0f/4096.0f), -8.0f), 8.0f - 1.0f/4096.0f);
    float qB1 = fminf(fmaxf(rintf(aB1*QC)*(1.0f/4096.0f), -8.0f), 8.0f - 1.0f/4096.0f);
    const float sgn = p ? -1.0f : 1.0f;
    oA0 = fmaf(qA0, sgn, oA0); oA1 = fmaf(qA1, sgn, oA1);
    oB0 = fmaf(qB0, sgn, oB0); oB1 = fmaf(qB1, sgn, oB1);
  }
#undef EPI

  // exact float atomics: all addends are multiples of 2^-12, partial sums < 2^8
  // -> every intermediate exactly representable -> order-independent & deterministic
  const int jout = jblk*32 + col;
  atomicAdd(&out[(bb + hi    )*128 + jout], hi ? oA1 : oA0);
  atomicAdd(&out[(bb + 2 + hi)*128 + jout], hi ? oB1 : oB0);
}

extern "C" void kernel_launch(void* const* d_in, const int* in_sizes, int n_in,
                              void* d_out, int out_size, void* d_ws, size_t ws_size,
                              hipStream_t stream){
  const float* x    = (const float*)d_in[0];
  const float* w    = (const float*)d_in[1];
  const float* bias = (const float*)d_in[2];
  uint8_t* ws = (uint8_t*)d_ws;
  float* out = (float*)d_out;

  hipLaunchKernelGGL(pack_k, dim3(1408), dim3(256), 0, stream,
                     x, w, bias, (uint4*)(ws + XM_OFF), (uint32_t*)(ws + BP_OFF),
                     (uint16_t*)(ws + MK_OFF), out);
  hipLaunchKernelGGL(mvm_main_k, dim3(16, 4, 8), dim3(512), 0, stream,
                     (const uint4*)(ws + XM_OFF), ws + BP_OFF,
                     (const uint16_t*)(ws + MK_OFF), out);
}

// Round 18
// 23.883 us; speedup vs baseline: 1.0221x; 1.0221x over previous
//
#include <hip/hip_runtime.h>
#include <stdint.h>

typedef __attribute__((ext_vector_type(4)))  int i32x4;
typedef __attribute__((ext_vector_type(16))) int i32x16;

// ws layout:
//   xm: uint4 [b=512][z=8][s=16]  (4 x u32 k-bitplanes)   1 MB
//   Bp: i8    [z=8][p=2][sl=8][j=128][k=128]              2 MB
//   mk: u16   [z=8][j=128]   live-tile mask               2 KB
#define XM_OFF 0u
#define BP_OFF 1048576u
#define MK_OFF 3145728u

typedef const __attribute__((address_space(1))) uint32_t* gas1_u32p;
typedef __attribute__((address_space(3))) uint32_t* las3_u32p;

__device__ __forceinline__ uint32_t q16(float v){
  float f = fminf(fmaxf(rintf(v*4096.f), -32768.f), 32767.f);
  return (uint32_t)(int)f & 0xffffu;
}

// ---------- fused pack: x -> bit-planes, w -> slice planes + per-j masks, out <- bias ----------
__global__ __launch_bounds__(256) void pack_k(const float* __restrict__ x, const float* __restrict__ w,
                                              const float* __restrict__ bias,
                                              uint4* __restrict__ xm, uint32_t* __restrict__ Bw,
                                              uint16_t* __restrict__ mk, float* __restrict__ out){
  const int lane = threadIdx.x & 63;
  if (blockIdx.x < 1024){
    // one wave per (b, z): transpose 128 xint16 values into 16 s-bitplanes of 4 u32
    int wv = blockIdx.x*4 + (threadIdx.x >> 6);       // 0..4095
    int b = wv >> 3, z = wv & 7;
    const float* xp = x + b*1024 + z*128;
    uint32_t u0 = q16(xp[lane]);
    uint32_t u1 = q16(xp[lane + 64]);
    uint4 out4 = {0,0,0,0};
    #pragma unroll
    for (int s = 0; s < 16; ++s){
      unsigned long long m0 = __ballot((u0 >> s) & 1u);
      unsigned long long m1 = __ballot((u1 >> s) & 1u);
      if (lane == s){
        out4.x = (uint32_t)m0; out4.y = (uint32_t)(m0 >> 32);
        out4.z = (uint32_t)m1; out4.w = (uint32_t)(m1 >> 32);
      }
    }
    if (lane < 16) xm[(b*8 + z)*16 + lane] = out4;
  } else if (blockIdx.x < 1152){
    int t = (blockIdx.x - 1024)*256 + threadIdx.x;    // 32768; one j per block
    int j = t >> 8, kq = t & 255;
    int r = kq >> 5, kd = kq & 31;                    // each 32-lane half: one r
    float4 v = *reinterpret_cast<const float4*>(w + j*1024 + kq*4);
    uint32_t lm = 0;
    #pragma unroll
    for (int p = 0; p < 2; ++p){
      uint32_t q0 = (uint32_t)fminf(rintf(fmaxf(p ? -v.x : v.x, 0.f)*4096.f), 65535.f);
      uint32_t q1 = (uint32_t)fminf(rintf(fmaxf(p ? -v.y : v.y, 0.f)*4096.f), 65535.f);
      uint32_t q2 = (uint32_t)fminf(rintf(fmaxf(p ? -v.z : v.z, 0.f)*4096.f), 65535.f);
      uint32_t q3 = (uint32_t)fminf(rintf(fmaxf(p ? -v.w : v.w, 0.f)*4096.f), 65535.f);
      #pragma unroll
      for (int sl = 0; sl < 8; ++sl){
        int sh = 2*(7 - sl);
        uint32_t word = ((q0 >> sh) & 3u) | (((q1 >> sh) & 3u) << 8)
                      | (((q2 >> sh) & 3u) << 16) | (((q3 >> sh) & 3u) << 24);
        Bw[(((r*2 + p)*8 + sl)*128 + j)*32 + kd] = word;
        lm |= (word != 0u ? 1u : 0u) << (p*8 + sl);
      }
    }
    // OR-reduce within each 32-lane half (half shares same (r, j))
    lm |= (uint32_t)__shfl_xor((int)lm, 16);
    lm |= (uint32_t)__shfl_xor((int)lm, 8);
    lm |= (uint32_t)__shfl_xor((int)lm, 4);
    lm |= (uint32_t)__shfl_xor((int)lm, 2);
    lm |= (uint32_t)__shfl_xor((int)lm, 1);
    if ((threadIdx.x & 31) == 0) mk[r*128 + j] = (uint16_t)lm;  // one writer per (z,j): race-free
  } else {
    // out <- bias rounded to 2^-12 grid: all later atomic adds are exact & order-free
    int t = (blockIdx.x - 1152)*256 + threadIdx.x;    // 65536
    out[t] = rintf(bias[t & 127]*4096.f)*(1.0f/4096.0f);
  }
}

// ---------- main MFMA kernel: r15 body + async global_load_lds staging (row term fixed) ----------
__global__ __launch_bounds__(512, 4) void mvm_main_k(const uint4* __restrict__ xm,
                                                     const uint8_t* __restrict__ Bp,
                                                     const uint16_t* __restrict__ mk,
                                                     float* __restrict__ out){
  __shared__ uint8_t lds[65536];                      // 16 (p,sl) slots x 4KB
  const int tid = threadIdx.x, lane = tid & 63, wid = tid >> 6;
  const int z = blockIdx.z, jblk = blockIdx.y;
  const int col = lane & 31, hi = lane >> 5;

  // ---- wave-uniform live mask for (z, jblk): OR of 32 per-j masks ----
  uint32_t mv = ((const uint32_t*)mk)[z*64 + jblk*16 + (lane & 15)];
  mv |= (uint32_t)__shfl_xor((int)mv, 1);
  mv |= (uint32_t)__shfl_xor((int)mv, 2);
  mv |= (uint32_t)__shfl_xor((int)mv, 4);
  mv |= (uint32_t)__shfl_xor((int)mv, 8);
  const uint32_t msk = (uint32_t)__builtin_amdgcn_readfirstlane((int)((mv | (mv >> 16)) & 0xFFFFu));

  // ---- async staging: DMA live tiles global->LDS ----
  // LDS dest: uniform base, HW writes at +lane*16 = q*128 + (lane&7)*16.
  // Global src per lane must match that row: + q*128 + ((lane&7)^q)*16  (swizzle on source, T21).
  {
    const int q = lane >> 3, cS = (lane & 7) ^ q;
    #pragma unroll
    for (int u = 0; u < 2; ++u){
      const int si = wid + u*8;
      if (msk & (1u << si)){
        const uint8_t* src = Bp + ((size_t)((z*16 + si)*128 + jblk*32) << 7) + q*128 + cS*16;
        uint8_t* dst = lds + si*4096;                 // rows q / q+8 / q+16 / q+24
        __builtin_amdgcn_global_load_lds((gas1_u32p)(const void*)(src          ),
                                         (las3_u32p)(void*)(dst        ), 16, 0, 0);
        __builtin_amdgcn_global_load_lds((gas1_u32p)(const void*)(src +  8*128 ),
                                         (las3_u32p)(void*)(dst + 1024), 16, 0, 0);
        __builtin_amdgcn_global_load_lds((gas1_u32p)(const void*)(src + 16*128 ),
                                         (las3_u32p)(void*)(dst + 2048), 16, 0, 0);
        __builtin_amdgcn_global_load_lds((gas1_u32p)(const void*)(src + 24*128 ),
                                         (las3_u32p)(void*)(dst + 3072), 16, 0, 0);
      }
    }
  }

  // ---- A fragments for TWO b-pairs (4 b per wave), verified mapping (overlaps the DMA) ----
  const int bb  = blockIdx.x*32 + wid*4;
  const int s_a = lane & 15;
  const uint4 pwA = xm[((bb     + (col >> 4))*8 + z)*16 + s_a];
  const uint4 pwB = xm[((bb + 2 + (col >> 4))*8 + z)*16 + s_a];
  i32x4 afrA[4], afrB[4];
  {
    const uint32_t wA[4] = {pwA.x, pwA.y, pwA.z, pwA.w};
    const uint32_t wB[4] = {pwB.x, pwB.y, pwB.z, pwB.w};
    #pragma unroll
    for (int f = 0; f < 4; ++f){
      uint32_t plA = wA[f] >> (hi*16);
      uint32_t plB = wB[f] >> (hi*16);
      #pragma unroll
      for (int wI = 0; wI < 4; ++wI){
        afrA[f][wI] = (int)((((plA >> (wI*4)) & 0xFu) * 0x204081u) & 0x01010101u);
        afrB[f][wI] = (int)((((plB >> (wI*4)) & 0xFu) * 0x204081u) & 0x01010101u);
      }
    }
  }
  __syncthreads();

  const int c7 = col & 7;
  const int xo0 = ((0 + hi) ^ c7) << 4;
  const int xo1 = ((2 + hi) ^ c7) << 4;
  const int xo2 = ((4 + hi) ^ c7) << 4;
  const int xo3 = ((6 + hi) ^ c7) << 4;

  i32x16 zz;
  #pragma unroll
  for (int i = 0; i < 16; ++i) zz[i] = 0;

  const float C1 = (float)(511.0/384.0);
  const float QC = (float)(384.0/511.0/4096.0);
  const float sc = hi ? 16.0f : 1.0f;                 // 2^(4*hi)
  const float w7 = hi ? -8.0f : 8.0f;                 // stream 15 (s_lo=11, hi=1) is negative
  float oA0 = 0.f, oA1 = 0.f, oB0 = 0.f, oB1 = 0.f;

  // wave-parity phase stagger: odd waves run p=1 first (scalar-uniform)
  const int pfirst = __builtin_amdgcn_readfirstlane(wid & 1);

#define EPI(cc, A0, A1) do { \
    float nf[16]; \
    _Pragma("unroll") \
    for (int g_ = 0; g_ < 16; ++g_) nf[g_] = rintf((float)cc[g_] * C1); \
    float t0 = fmaf(nf[1], 2.f, nf[0]);  t0 = fmaf(nf[2], 4.f, t0);  t0 = fmaf(nf[3], 8.f, t0); \
    float t1 = fmaf(nf[5], 2.f, nf[4]);  t1 = fmaf(nf[6], 4.f, t1);  t1 = fmaf(nf[7], w7, t1); \
    float t2 = fmaf(nf[9], 2.f, nf[8]);  t2 = fmaf(nf[10],4.f, t2);  t2 = fmaf(nf[11],8.f, t2); \
    float t3 = fmaf(nf[13],2.f, nf[12]); t3 = fmaf(nf[14],4.f, t3);  t3 = fmaf(nf[15],w7, t3); \
    A0 = fmaf(t0, slwv, A0);  A0 = fmaf(t1, slw256, A0); \
    A1 = fmaf(t2, slwv, A1);  A1 = fmaf(t3, slw256, A1); \
  } while (0)

  #pragma unroll
  for (int pi = 0; pi < 2; ++pi){
    const int p = pi ^ pfirst;                        // scalar-uniform
    const int tbase = p*8;
    float aA0 = 0.f, aA1 = 0.f, aB0 = 0.f, aB1 = 0.f;
    #pragma unroll
    for (int sl = 0; sl < 8; ++sl){
      if (msk & (1u << (tbase + sl))){
        const float slwv   = (float)(1 << (14 - 2*sl));  // 4^(7-sl)
        const float slw256 = slwv * 256.0f;
        const uint8_t* lb = lds + (size_t)(tbase + sl)*4096 + col*128;
        i32x4 b0 = *(const i32x4*)(lb + xo0);
        i32x4 b1 = *(const i32x4*)(lb + xo1);
        i32x4 b2 = *(const i32x4*)(lb + xo2);
        i32x4 b3 = *(const i32x4*)(lb + xo3);
        // interleaved independent chains: matrix pipe gets an issue-ready MFMA every slot
        i32x16 cc = __builtin_amdgcn_mfma_i32_32x32x32_i8(afrA[0], b0, zz, 0, 0, 0);
        i32x16 cd = __builtin_amdgcn_mfma_i32_32x32x32_i8(afrB[0], b0, zz, 0, 0, 0);
        cc = __builtin_amdgcn_mfma_i32_32x32x32_i8(afrA[1], b1, cc, 0, 0, 0);
        cd = __builtin_amdgcn_mfma_i32_32x32x32_i8(afrB[1], b1, cd, 0, 0, 0);
        cc = __builtin_amdgcn_mfma_i32_32x32x32_i8(afrA[2], b2, cc, 0, 0, 0);
        cd = __builtin_amdgcn_mfma_i32_32x32x32_i8(afrB[2], b2, cd, 0, 0, 0);
        cc = __builtin_amdgcn_mfma_i32_32x32x32_i8(afrA[3], b3, cc, 0, 0, 0);
        cd = __builtin_amdgcn_mfma_i32_32x32x32_i8(afrB[3], b3, cd, 0, 0, 0);
        EPI(cc, aA0, aA1);
        EPI(cd, aB0, aB1);
      }
    }

    aA0 *= sc; aA1 *= sc; aB0 *= sc; aB1 *= sc;
    aA0 += __shfl_xor(aA0, 32); aA1 += __shfl_xor(aA1, 32);
    aB0 += __shfl_xor(aB0, 32); aB1 += __shfl_xor(aB1, 32);

    float qA0 = fminf(fmaxf(rintf(aA0*QC)*(1.0f/4096.0f), -8.0f), 8.0f - 1.0f/4096.0f);
    float qA1 = fminf(fmaxf(rintf(aA1*QC)*(1.0f/4096.0f), -8.0f), 8.0f - 1.0f/4096.0f);
    float qB0 = fminf(fmaxf(rintf(aB0*QC)*(1.0f/4096.0f), -8.0f), 8.0f - 1.0f/4096.0f);
    float qB1 = fminf(fmaxf(rintf(aB1*QC)*(1.0f/4096.0f), -8.0f), 8.0f - 1.0f/4096.0f);
    const float sgn = p ? -1.0f : 1.0f;
    oA0 = fmaf(qA0, sgn, oA0); oA1 = fmaf(qA1, sgn, oA1);
    oB0 = fmaf(qB0, sgn, oB0); oB1 = fmaf(qB1, sgn, oB1);
  }
#undef EPI

  // exact float atomics: all addends are multiples of 2^-12, partial sums < 2^8
  // -> every intermediate exactly representable -> order-independent & deterministic
  const int jout = jblk*32 + col;
  atomicAdd(&out[(bb + hi    )*128 + jout], hi ? oA1 : oA0);
  atomicAdd(&out[(bb + 2 + hi)*128 + jout], hi ? oB1 : oB0);
}

extern "C" void kernel_launch(void* const* d_in, const int* in_sizes, int n_in,
                              void* d_out, int out_size, void* d_ws, size_t ws_size,
                              hipStream_t stream){
  const float* x    = (const float*)d_in[0];
  const float* w    = (const float*)d_in[1];
  const float* bias = (const float*)d_in[2];
  uint8_t* ws = (uint8_t*)d_ws;
  float* out = (float*)d_out;

  hipLaunchKernelGGL(pack_k, dim3(1408), dim3(256), 0, stream,
                     x, w, bias, (uint4*)(ws + XM_OFF), (uint32_t*)(ws + BP_OFF),
                     (uint16_t*)(ws + MK_OFF), out);
  hipLaunchKernelGGL(mvm_main_k, dim3(16, 4, 8), dim3(512), 0, stream,
                     (const uint4*)(ws + XM_OFF), ws + BP_OFF,
                     (const uint16_t*)(ws + MK_OFF), out);
}